// Round 1
// 1066.973 us; speedup vs baseline: 2.0691x; 2.0691x over previous
//
#include <hip/hip_runtime.h>
#include <cstddef>

#define BB 64
#define SS 256
#define DD 1024
#define MM (BB * SS)  // 16384

typedef unsigned short u16;
typedef short bf16x8 __attribute__((ext_vector_type(8)));
typedef float f32x4 __attribute__((ext_vector_type(4)));

#define LDSTRIDE 40  // 32 k-elems + 8 pad: start dwords tile banks every 4 -> conflict-free b128 r/w

__device__ __forceinline__ float silu_f(float v) {
    return v * (1.0f / (1.0f + __expf(-v)));
}

// Split two fp32 into a packed bf16-hi pair and bf16-lo pair (truncation split).
// hi = f & 0xFFFF0000 (exact), lo = f - hi (exact fp32 sub), lo truncated to bf16.
// Dropped bits ~2^-16 relative -> bf16x3 product error ~1e-3 absolute on this data.
__device__ __forceinline__ void split2(float f0, float f1, unsigned& hp, unsigned& lp) {
    const unsigned b0 = __float_as_uint(f0), b1 = __float_as_uint(f1);
    const unsigned h0 = b0 & 0xFFFF0000u, h1 = b1 & 0xFFFF0000u;
    const float l0 = f0 - __uint_as_float(h0);
    const float l1 = f1 - __uint_as_float(h1);
    hp = (h0 >> 16) | h1;
    lp = (__float_as_uint(l0) >> 16) | (__float_as_uint(l1) & 0xFFFF0000u);
}

// ---------------------------------------------------------------------------
// NT GEMM via bf16x3 MFMA: C[M,N] = A[M,K] @ B[N,K]^T
//   SILU_A: apply silu() to A elements while staging
//   EPI 0: C = acc + bias[c]
//   EPI 1: C = t0*scale[b,c] + shift[b,c] + acc + bias[c]   (adain(t0) + fc)
//   EPI 2: C = resid + silu(acc + bias[c])
// 128x128 tile, BK=32, 256 threads = 4 waves (2x2), 4x4 16x16x32 frags/wave.
// Each fp32 operand split hi/lo bf16; acc += Ah*Bh + Ah*Bl + Al*Bh (fp32 acc).
// ---------------------------------------------------------------------------
template<bool SILU_A, int EPI>
__global__ __launch_bounds__(256, 2)
void gemm_nt_mfma(const float* __restrict__ A, const float* __restrict__ Bw,
                  const float* __restrict__ bias,
                  const float* __restrict__ t0, const float* __restrict__ scl,
                  const float* __restrict__ shf, const float* __restrict__ resid,
                  float* __restrict__ C, int M, int N, int K)
{
    __shared__ u16 lds[4 * 128 * LDSTRIDE];  // 40 KB: Ah, Al, Bh, Bl tiles
    u16* Ah = lds;
    u16* Al = lds + 128 * LDSTRIDE;
    u16* Bh = lds + 2 * 128 * LDSTRIDE;
    u16* Bl = lds + 3 * 128 * LDSTRIDE;

    // XCD-aware bijective swizzle (nwg % 8 == 0 here): the 8 col-blocks that
    // share an A row-panel land on the same XCD's L2.
    const int nbx = gridDim.x;
    const int nwg = nbx * gridDim.y;
    int lin = blockIdx.y * nbx + blockIdx.x;
    if ((nwg & 7) == 0) {
        const int cpx = nwg >> 3;
        lin = (lin & 7) * cpx + (lin >> 3);
    }
    const int bx = lin % nbx;
    const int by = lin / nbx;
    const int row0 = by * 128;
    const int col0 = bx * 128;

    const int tid  = threadIdx.x;
    const int srow = tid >> 1;         // 0..127: tile row for staging
    const int sko  = (tid & 1) << 4;   // 0 or 16: k-offset for staging
    const int wbase = srow * LDSTRIDE + sko;

    const float* Ag = A  + (size_t)(row0 + srow) * K + sko;
    const float* Bg = Bw + (size_t)(col0 + srow) * K + sko;

    const int lane = tid & 63;
    const int wid  = tid >> 6;         // 0..3
    const int wr = wid >> 1, wc = wid & 1;
    const int fr = lane & 15;          // A-row / B-col within fragment
    const int fh = lane >> 4;          // k-chunk 0..3 (8 bf16 each)
    const int abase = (wr * 64 + fr) * LDSTRIDE + fh * 8;
    const int bbase = (wc * 64 + fr) * LDSTRIDE + fh * 8;

    f32x4 acc[4][4];
    const f32x4 zero = {0.f, 0.f, 0.f, 0.f};
#pragma unroll
    for (int i = 0; i < 4; ++i)
#pragma unroll
        for (int j = 0; j < 4; ++j) acc[i][j] = zero;

    for (int k0 = 0; k0 < K; k0 += 32) {
        // --- load + convert in registers (no LDS touch before barrier) ---
        float4 va[4], vb[4];
#pragma unroll
        for (int q = 0; q < 4; ++q) va[q] = *(const float4*)(Ag + k0 + q * 4);
#pragma unroll
        for (int q = 0; q < 4; ++q) vb[q] = *(const float4*)(Bg + k0 + q * 4);
        if (SILU_A) {
#pragma unroll
            for (int q = 0; q < 4; ++q) {
                va[q].x = silu_f(va[q].x); va[q].y = silu_f(va[q].y);
                va[q].z = silu_f(va[q].z); va[q].w = silu_f(va[q].w);
            }
        }
        uint4 ah0, al0, ah1, al1, bh0, bl0, bh1, bl1;
        split2(va[0].x, va[0].y, ah0.x, al0.x); split2(va[0].z, va[0].w, ah0.y, al0.y);
        split2(va[1].x, va[1].y, ah0.z, al0.z); split2(va[1].z, va[1].w, ah0.w, al0.w);
        split2(va[2].x, va[2].y, ah1.x, al1.x); split2(va[2].z, va[2].w, ah1.y, al1.y);
        split2(va[3].x, va[3].y, ah1.z, al1.z); split2(va[3].z, va[3].w, ah1.w, al1.w);
        split2(vb[0].x, vb[0].y, bh0.x, bl0.x); split2(vb[0].z, vb[0].w, bh0.y, bl0.y);
        split2(vb[1].x, vb[1].y, bh0.z, bl0.z); split2(vb[1].z, vb[1].w, bh0.w, bl0.w);
        split2(vb[2].x, vb[2].y, bh1.x, bl1.x); split2(vb[2].z, vb[2].w, bh1.y, bl1.y);
        split2(vb[3].x, vb[3].y, bh1.z, bl1.z); split2(vb[3].z, vb[3].w, bh1.w, bl1.w);

        __syncthreads();  // previous iteration's fragment reads complete
        *(uint4*)&Ah[wbase] = ah0;  *(uint4*)&Ah[wbase + 8] = ah1;
        *(uint4*)&Al[wbase] = al0;  *(uint4*)&Al[wbase + 8] = al1;
        *(uint4*)&Bh[wbase] = bh0;  *(uint4*)&Bh[wbase + 8] = bh1;
        *(uint4*)&Bl[wbase] = bl0;  *(uint4*)&Bl[wbase + 8] = bl1;
        __syncthreads();

        // --- fragment loads + MFMA ---
        bf16x8 fah[4], fal[4];
#pragma unroll
        for (int i = 0; i < 4; ++i) {
            fah[i] = *(const bf16x8*)&Ah[abase + i * 16 * LDSTRIDE];
            fal[i] = *(const bf16x8*)&Al[abase + i * 16 * LDSTRIDE];
        }
#pragma unroll
        for (int j = 0; j < 4; ++j) {
            const bf16x8 fbh = *(const bf16x8*)&Bh[bbase + j * 16 * LDSTRIDE];
            const bf16x8 fbl = *(const bf16x8*)&Bl[bbase + j * 16 * LDSTRIDE];
#pragma unroll
            for (int i = 0; i < 4; ++i) {
                acc[i][j] = __builtin_amdgcn_mfma_f32_16x16x32_bf16(fah[i], fbh, acc[i][j], 0, 0, 0);
                acc[i][j] = __builtin_amdgcn_mfma_f32_16x16x32_bf16(fal[i], fbh, acc[i][j], 0, 0, 0);
                acc[i][j] = __builtin_amdgcn_mfma_f32_16x16x32_bf16(fah[i], fbl, acc[i][j], 0, 0, 0);
            }
        }
    }

    // Epilogue. C/D layout (m89/m91-verified): col = lane&15, row = (lane>>4)*4 + reg.
#pragma unroll
    for (int i = 0; i < 4; ++i) {
        const int rbase = row0 + wr * 64 + i * 16 + fh * 4;
#pragma unroll
        for (int j = 0; j < 4; ++j) {
            const int c = col0 + wc * 64 + j * 16 + fr;
            const float bsum = bias[c];
            float sc = 0.f, sh = 0.f;
            if (EPI == 1) {
                const int b = rbase >> 8;  // rows are b*256+s
                sc = scl[b * DD + c];
                sh = shf[b * DD + c];
            }
#pragma unroll
            for (int r = 0; r < 4; ++r) {
                const int rr = rbase + r;
                const size_t idx = (size_t)rr * N + c;
                const float t = acc[i][j][r] + bsum;
                if (EPI == 0) {
                    C[idx] = t;
                } else if (EPI == 1) {
                    C[idx] = fmaf(t0[idx], sc, sh) + t;
                } else {
                    C[idx] = resid[idx] + silu_f(t);
                }
            }
        }
    }
}

// ---------------------------------------------------------------------------
// Batched NN GEMM over the seq axis (fp32 VALU; K=256, ~6% of total FLOPs):
// X[b,t,d] = X[b,t,d] + silu( sum_s W0[t,s]*Y[b,s,d] + b0[t] )
// ---------------------------------------------------------------------------
__global__ __launch_bounds__(256)
void gemm_seq(const float* __restrict__ W0, const float* __restrict__ Y,
              const float* __restrict__ bias0, float* __restrict__ X)
{
    __shared__ float As[16][132];
    __shared__ float Bs[16][132];
    const int tid   = threadIdx.x;
    const int batch = blockIdx.z;
    const int row0  = blockIdx.y * 128;  // t
    const int col0  = blockIdx.x * 128;  // d
    const float* Bg = Y + (size_t)batch * SS * DD;
    float* Cb = X + (size_t)batch * SS * DD;
    const int lrA = tid >> 1;
    const int lkA = (tid & 1) * 8;
    const int kB  = tid >> 4;         // 0..15
    const int nB  = (tid & 15) * 8;   // 0..120
    const int ty = tid >> 4;
    const int tx = tid & 15;

    float acc[8][8];
#pragma unroll
    for (int i = 0; i < 8; ++i)
#pragma unroll
        for (int j = 0; j < 8; ++j) acc[i][j] = 0.0f;

    for (int k0 = 0; k0 < SS; k0 += 16) {
        const float* ap = &W0[(size_t)(row0 + lrA) * SS + k0 + lkA];
        float4 a0 = *(const float4*)(ap);
        float4 a1 = *(const float4*)(ap + 4);
        const float* bp = &Bg[(size_t)(k0 + kB) * DD + col0 + nB];
        float4 b0 = *(const float4*)(bp);
        float4 b1 = *(const float4*)(bp + 4);
        As[lkA+0][lrA] = a0.x; As[lkA+1][lrA] = a0.y; As[lkA+2][lrA] = a0.z; As[lkA+3][lrA] = a0.w;
        As[lkA+4][lrA] = a1.x; As[lkA+5][lrA] = a1.y; As[lkA+6][lrA] = a1.z; As[lkA+7][lrA] = a1.w;
        *(float4*)&Bs[kB][nB]     = b0;
        *(float4*)&Bs[kB][nB + 4] = b1;
        __syncthreads();
#pragma unroll
        for (int k = 0; k < 16; ++k) {
            const float4 ra0 = *(const float4*)&As[k][ty * 8];
            const float4 ra1 = *(const float4*)&As[k][ty * 8 + 4];
            const float4 rb0 = *(const float4*)&Bs[k][tx * 8];
            const float4 rb1 = *(const float4*)&Bs[k][tx * 8 + 4];
            const float ra[8] = {ra0.x, ra0.y, ra0.z, ra0.w, ra1.x, ra1.y, ra1.z, ra1.w};
            const float rb[8] = {rb0.x, rb0.y, rb0.z, rb0.w, rb1.x, rb1.y, rb1.z, rb1.w};
#pragma unroll
            for (int i = 0; i < 8; ++i)
#pragma unroll
                for (int j = 0; j < 8; ++j)
                    acc[i][j] = fmaf(ra[i], rb[j], acc[i][j]);
        }
        __syncthreads();
    }

#pragma unroll
    for (int i = 0; i < 8; ++i) {
        const int r = row0 + ty * 8 + i;       // t within batch
        const float bt = bias0[r];
        const size_t rowbase = (size_t)r * DD;
#pragma unroll
        for (int jj = 0; jj < 8; jj += 4) {
            const int c0 = col0 + tx * 8 + jj;
            float4 res = *(const float4*)&Cb[rowbase + c0];
            float4 o;
            o.x = res.x + silu_f(acc[i][jj + 0] + bt);
            o.y = res.y + silu_f(acc[i][jj + 1] + bt);
            o.z = res.z + silu_f(acc[i][jj + 2] + bt);
            o.w = res.w + silu_f(acc[i][jj + 3] + bt);
            *(float4*)&Cb[rowbase + c0] = o;
        }
    }
}

// ---------------------------------------------------------------------------
// AdaIN stats: per (b,d) channel over s: scale = s_std/c_std, shift = s_mean - c_mean*scale
// ---------------------------------------------------------------------------
__global__ __launch_bounds__(256)
void adain_stats(const float* __restrict__ t0, const float* __restrict__ style,
                 float* __restrict__ scl, float* __restrict__ shf)
{
    const int idx = blockIdx.x * 256 + threadIdx.x;  // 0..65535
    const int b = idx >> 10;
    const int d = idx & (DD - 1);
    const float* pc = t0    + (size_t)b * SS * DD + d;
    const float* ps = style + (size_t)b * SS * DD + d;
    float sc = 0.f, sc2 = 0.f, ss = 0.f, ss2 = 0.f;
    for (int s = 0; s < SS; ++s) {
        const float c  = pc[(size_t)s * DD];
        const float st = ps[(size_t)s * DD];
        sc += c;  sc2 = fmaf(c, c, sc2);
        ss += st; ss2 = fmaf(st, st, ss2);
    }
    const float mc = sc * (1.0f / SS);
    const float ms = ss * (1.0f / SS);
    float vc = (sc2 - (float)SS * mc * mc) * (1.0f / (SS - 1));
    float vs = (ss2 - (float)SS * ms * ms) * (1.0f / (SS - 1));
    vc = fmaxf(vc, 0.f);
    vs = fmaxf(vs, 0.f);
    const float csd = sqrtf(vc + 1e-5f);
    const float ssd = sqrtf(vs + 1e-5f);
    const float sca = ssd / csd;
    scl[idx] = sca;
    shf[idx] = ms - mc * sca;
}

// ---------------------------------------------------------------------------
// LayerNorm over last dim (D=1024): one wave per row.
// ---------------------------------------------------------------------------
__global__ __launch_bounds__(256)
void ln_rows(const float* __restrict__ X, const float* __restrict__ g,
             const float* __restrict__ beta, float* __restrict__ Y)
{
    const int row  = blockIdx.x * 4 + (threadIdx.x >> 6);
    const int lane = threadIdx.x & 63;
    const float* xr = X + (size_t)row * DD;
    float4 v[4];
    float sum = 0.f, sq = 0.f;
#pragma unroll
    for (int c = 0; c < 4; ++c) {
        v[c] = *(const float4*)&xr[c * 256 + lane * 4];
        sum += v[c].x + v[c].y + v[c].z + v[c].w;
        sq  += v[c].x * v[c].x + v[c].y * v[c].y + v[c].z * v[c].z + v[c].w * v[c].w;
    }
#pragma unroll
    for (int off = 32; off > 0; off >>= 1) {
        sum += __shfl_down(sum, off, 64);
        sq  += __shfl_down(sq,  off, 64);
    }
    sum = __shfl(sum, 0, 64);
    sq  = __shfl(sq,  0, 64);
    const float mu = sum * (1.0f / DD);
    float var = sq * (1.0f / DD) - mu * mu;
    var = fmaxf(var, 0.f);
    const float rs = rsqrtf(var + 1e-5f);
    float* yr = Y + (size_t)row * DD;
#pragma unroll
    for (int c = 0; c < 4; ++c) {
        const int col = c * 256 + lane * 4;
        const float4 gv = *(const float4*)&g[col];
        const float4 bv = *(const float4*)&beta[col];
        float4 o;
        o.x = (v[c].x - mu) * rs * gv.x + bv.x;
        o.y = (v[c].y - mu) * rs * gv.y + bv.y;
        o.z = (v[c].z - mu) * rs * gv.z + bv.z;
        o.w = (v[c].w - mu) * rs * gv.w + bv.w;
        *(float4*)&yr[col] = o;
    }
}

// ---------------------------------------------------------------------------
// Copy embed/style passthrough outputs (float4, grid-stride).
// ---------------------------------------------------------------------------
__global__ __launch_bounds__(256)
void copy_pass(const float4* __restrict__ emb, const float4* __restrict__ sty,
               float4* __restrict__ out_emb, float4* __restrict__ out_sty)
{
    const int n4 = MM * DD / 4;  // 4194304
    const int stride = gridDim.x * blockDim.x;
    for (int i = blockIdx.x * blockDim.x + threadIdx.x; i < n4; i += stride) {
        out_emb[i] = emb[i];
        out_sty[i] = sty[i];
    }
}

extern "C" void kernel_launch(void* const* d_in, const int* in_sizes, int n_in,
                              void* d_out, int out_size, void* d_ws, size_t ws_size,
                              hipStream_t stream)
{
    const float* x     = (const float*)d_in[0];
    const float* embed = (const float*)d_in[1];
    const float* style = (const float*)d_in[2];
    const float* Wc    = (const float*)d_in[3];
    const float* bc    = (const float*)d_in[4];
    const float* We    = (const float*)d_in[5];
    const float* be    = (const float*)d_in[6];
    const float* W0    = (const float*)d_in[7];
    const float* b0    = (const float*)d_in[8];
    const float* W1    = (const float*)d_in[9];
    const float* b1    = (const float*)d_in[10];
    const float* g0    = (const float*)d_in[11];
    const float* beta0 = (const float*)d_in[12];
    const float* g1    = (const float*)d_in[13];
    const float* beta1 = (const float*)d_in[14];

    float* out     = (float*)d_out;
    float* out_x   = out;                    // final x
    float* out_emb = out + (size_t)MM * DD;  // embed passthrough (scratch buf1 until end)
    float* out_sty = out + (size_t)2 * MM * DD;  // style passthrough (scratch buf0 until end)

    float* buf0 = out_sty;  // t0 -> y -> z
    float* buf1 = out_emb;  // x1 -> x2 (in place)
    float* scl = (float*)d_ws;          // [B*D]
    float* shf = scl + BB * DD;         // [B*D]

    const dim3 gNT(DD / 128, MM / 128);  // (8, 128)

    // 1) t0 = x @ Wc^T + bc
    gemm_nt_mfma<false, 0><<<gNT, 256, 0, stream>>>(x, Wc, bc, nullptr, nullptr, nullptr,
                                                    nullptr, buf0, MM, DD, 2 * DD);
    // 2) AdaIN stats of (t0, style) -> scale/shift per (b,d)
    adain_stats<<<BB * DD / 256, 256, 0, stream>>>(buf0, style, scl, shf);
    // 3) x1 = adain(t0) + silu(embed) @ We^T + be
    gemm_nt_mfma<true, 1><<<gNT, 256, 0, stream>>>(embed, We, be, buf0, scl, shf,
                                                   nullptr, buf1, MM, DD, DD);
    // 4) y = LN(x1; g0, beta0)
    ln_rows<<<MM / 4, 256, 0, stream>>>(buf1, g0, beta0, buf0);
    // 5) x2 = x1 + silu(W0 @ y + b0)   (in-place on buf1)
    gemm_seq<<<dim3(DD / 128, SS / 128, BB), 256, 0, stream>>>(W0, buf0, b0, buf1);
    // 6) z = LN(x2; g1, beta1)
    ln_rows<<<MM / 4, 256, 0, stream>>>(buf1, g1, beta1, buf0);
    // 7) out_x = x2 + silu(z @ W1^T + b1)
    gemm_nt_mfma<false, 2><<<gNT, 256, 0, stream>>>(buf0, W1, b1, nullptr, nullptr, nullptr,
                                                    buf1, out_x, MM, DD, DD);
    // 8) passthrough outputs (overwrites the scratch regions last)
    copy_pass<<<4096, 256, 0, stream>>>((const float4*)embed, (const float4*)style,
                                        (float4*)out_emb, (float4*)out_sty);
}

// Round 3
// 988.211 us; speedup vs baseline: 2.2340x; 1.0797x over previous
//
#include <hip/hip_runtime.h>
#include <cstddef>
#include <cstdint>

#define BB 64
#define SS 256
#define DD 1024
#define MM (BB * SS)  // 16384

typedef unsigned short u16;
typedef unsigned int u32;
typedef short bf16x8 __attribute__((ext_vector_type(8)));
typedef float f32x4 __attribute__((ext_vector_type(4)));

__device__ __forceinline__ float silu_f(float v) {
    return v * (1.0f / (1.0f + __expf(-v)));
}

// chunk swizzle: physical 16B-chunk = (c&~3) | ((c&3) ^ swz4(row&15))
__device__ __forceinline__ int swz4(int r) {
    return ((r >> 2) & 3) ^ (r & 3);
}

// truncation split: f = hi(bf16) + lo(bf16) + O(2^-16 rel)
__device__ __forceinline__ void splitf(float f, u16& h, u16& l) {
    const u32 b = __float_as_uint(f);
    const u32 hb = b & 0xFFFF0000u;
    const float lf = f - __uint_as_float(hb);
    h = (u16)(hb >> 16);
    l = (u16)(__float_as_uint(lf) >> 16);
}

// async global->LDS, 16B per lane; LDS dest wave-uniform base + lane*16
__device__ __forceinline__ void gll16(const void* g, void* l) {
    __builtin_amdgcn_global_load_lds(
        (const __attribute__((address_space(1))) u32*)g,
        (__attribute__((address_space(3))) u32*)l, 16, 0, 0);
}

// pack 16 floats into hi/lo bf16 uint4 pairs
__device__ __forceinline__ void cvt16(const float* av, uint4& h0, uint4& h1,
                                      uint4& l0, uint4& l1) {
    u16 hh[16], hl[16];
#pragma unroll
    for (int m = 0; m < 16; ++m) splitf(av[m], hh[m], hl[m]);
    u32 ph[8], pl[8];
#pragma unroll
    for (int m = 0; m < 8; ++m) {
        ph[m] = (u32)hh[2 * m] | ((u32)hh[2 * m + 1] << 16);
        pl[m] = (u32)hl[2 * m] | ((u32)hl[2 * m + 1] << 16);
    }
    h0 = make_uint4(ph[0], ph[1], ph[2], ph[3]);
    h1 = make_uint4(ph[4], ph[5], ph[6], ph[7]);
    l0 = make_uint4(pl[0], pl[1], pl[2], pl[3]);
    l1 = make_uint4(pl[4], pl[5], pl[6], pl[7]);
}

// ---------------------------------------------------------------------------
// Weight pre-split: src fp32 [N][K] -> dh/dl bf16 [N][K], chunk-swizzled so
// linear global_load_lds staging yields conflict-free swizzled LDS tiles.
// One thread = one 16B output chunk (8 elems). K/8 = 1<<k8shift (pow2).
// ---------------------------------------------------------------------------
__global__ __launch_bounds__(256)
void split_w(const float* __restrict__ src, u16* __restrict__ dh,
             u16* __restrict__ dl, int k8shift)
{
    const int idx = blockIdx.x * 256 + threadIdx.x;  // physical chunk id
    const int n = idx >> k8shift;
    const int c = idx & ((1 << k8shift) - 1);
    const int srcc = (c & ~3) | ((c & 3) ^ swz4(n & 15));  // logical chunk
    const float* sp = src + ((size_t)n << (k8shift + 3)) + srcc * 8;
    const float4 v0 = *(const float4*)sp;
    const float4 v1 = *(const float4*)(sp + 4);
    const float av[8] = {v0.x, v0.y, v0.z, v0.w, v1.x, v1.y, v1.z, v1.w};
    u16 hh[8], hl[8];
#pragma unroll
    for (int m = 0; m < 8; ++m) splitf(av[m], hh[m], hl[m]);
    u32 ph[4], pl[4];
#pragma unroll
    for (int m = 0; m < 4; ++m) {
        ph[m] = (u32)hh[2 * m] | ((u32)hh[2 * m + 1] << 16);
        pl[m] = (u32)hl[2 * m] | ((u32)hl[2 * m + 1] << 16);
    }
    *(uint4*)&dh[(size_t)idx * 8] = make_uint4(ph[0], ph[1], ph[2], ph[3]);
    *(uint4*)&dl[(size_t)idx * 8] = make_uint4(pl[0], pl[1], pl[2], pl[3]);
}

// ---------------------------------------------------------------------------
// NT GEMM via bf16x3 MFMA: C[M,N] = A[M,K] @ B[N,K]^T
// AM 0: A pre-split hi/lo, staged via global_load_lds (source chunk-swizzled)
// AM 1: A fp32, in-kernel convert + swizzled LDS write
// AM 2: like 1 with silu(A)
// BM 0: B pre-split, staged via global_load_lds (source chunk-swizzled)
// BM 1: B fp32, in-kernel convert + swizzled LDS write
// EPI 0: C = acc + bias[c]
// EPI 1: C = t0*scl[b,c] + shf[b,c] + acc + bias[c]
// EPI 2: C = resid + silu(acc + bias[c])
// EPI 3: C = resid + silu(acc + bias[row])   (row bias; batched)
// 128x128 tile, BK=32, 4 waves (2x2), 4x4 16x16x32 frags, 32KB LDS.
// ---------------------------------------------------------------------------
template<int AM, int BM, int EPI>
__global__ __launch_bounds__(256, (AM == 0 && BM == 0) ? 4 : 3)
void gemm_bf3(const float* __restrict__ A32,
              const u16* __restrict__ Ahg, const u16* __restrict__ Alg,
              const float* __restrict__ B32,
              const u16* __restrict__ Bhg, const u16* __restrict__ Blg,
              const float* __restrict__ bias,
              const float* __restrict__ t0, const float* __restrict__ scl,
              const float* __restrict__ shf,
              const float* __restrict__ resid, float* __restrict__ C,
              int M, int N, int K, long long bsB, long long bsC)
{
    __shared__ u16 lds[16384];  // bytes: Ah[0,8K) Al[8K,16K) Bh[16K,24K) Bl[24K,32K)

    const int z = blockIdx.z;
    const int nbx = gridDim.x;
    const int nwg = nbx * gridDim.y;
    int lin = blockIdx.y * nbx + blockIdx.x;
    if ((nwg & 7) == 0) {          // bijective XCD swizzle
        const int cpx = nwg >> 3;
        lin = (lin & 7) * cpx + (lin >> 3);
    }
    const int bx = lin % nbx;
    const int by = lin / nbx;
    const int row0 = by * 128, col0 = bx * 128;

    const int tid = threadIdx.x;
    const int lane = tid & 63, wid = tid >> 6;
    const int wr = wid >> 1, wc = wid & 1;
    const int fr = lane & 15, fh = lane >> 4;
    const int fsw = (fh ^ swz4(fr)) * 8;   // fragment chunk offset (u16)

    // convert-path staging geometry (each thread: one row-half = 16 elems)
    const int srow = tid >> 1;
    const int sko = (tid & 1) << 4;
    const int ssw = swz4(srow & 15);
    const int sw0 = srow * 32 + (((sko >> 3) + 0) ^ ssw) * 8;
    const int sw1 = srow * 32 + (((sko >> 3) + 1) ^ ssw) * 8;

    const float* Ag32 = nullptr;
    const float* Bg32 = nullptr;
    if constexpr (AM != 0) Ag32 = A32 + (size_t)(row0 + srow) * K + sko;
    if constexpr (BM != 0) Bg32 = B32 + (size_t)(col0 + srow) * K + sko;

    const u16* gPre = nullptr; int ldsPre = 0;   // AM==0 per-wave gll source
    const u16* gB = nullptr; int ldsB = 0, sib0 = 0;  // AM!=0 B gll

    if constexpr (AM == 0) {
        if constexpr (BM == 0) {
            const u16* gs; int base, lb;
            if (wid == 0)      { gs = Ahg; base = row0; lb = 0; }
            else if (wid == 1) { gs = Alg; base = row0; lb = 4096; }
            else if (wid == 2) { gs = Bhg + (size_t)z * (size_t)bsB; base = col0; lb = 8192; }
            else               { gs = Blg + (size_t)z * (size_t)bsB; base = col0; lb = 12288; }
            gPre = gs + (size_t)(base + (lane >> 2)) * K + (lane & 3) * 8;
            ldsPre = lb;
        } else {
            const u16* gs = (wid & 1) ? Alg : Ahg;
            gPre = gs + (size_t)(row0 + (lane >> 2)) * K + (lane & 3) * 8;
            ldsPre = (wid & 1) ? 4096 : 0;   // only wid<2 issues
        }
    } else {
        // BM==0 here: waves 0,1 -> Bh halves; waves 2,3 -> Bl halves
        gB = ((wid < 2) ? Bhg : Blg) + (size_t)z * (size_t)bsB
             + (size_t)(col0 + (wid & 1) * 64 + (lane >> 2)) * K + (lane & 3) * 8;
        ldsB = (wid < 2) ? 8192 : 12288;
        sib0 = (wid & 1) * 4;
    }

    f32x4 acc[4][4];
#pragma unroll
    for (int i = 0; i < 4; ++i)
#pragma unroll
        for (int j = 0; j < 4; ++j) acc[i][j] = (f32x4){0.f, 0.f, 0.f, 0.f};

    for (int k0 = 0; k0 < K; k0 += 32) {
        float av[16], bv[16];
        if constexpr (AM != 0) {
            const float4 a0 = *(const float4*)(Ag32 + k0);
            const float4 a1 = *(const float4*)(Ag32 + k0 + 4);
            const float4 a2 = *(const float4*)(Ag32 + k0 + 8);
            const float4 a3 = *(const float4*)(Ag32 + k0 + 12);
            av[0]=a0.x; av[1]=a0.y; av[2]=a0.z; av[3]=a0.w;
            av[4]=a1.x; av[5]=a1.y; av[6]=a1.z; av[7]=a1.w;
            av[8]=a2.x; av[9]=a2.y; av[10]=a2.z; av[11]=a2.w;
            av[12]=a3.x; av[13]=a3.y; av[14]=a3.z; av[15]=a3.w;
            if constexpr (AM == 2) {
#pragma unroll
                for (int m = 0; m < 16; ++m) av[m] = silu_f(av[m]);
            }
        }
        if constexpr (BM != 0) {
            const float4 b0 = *(const float4*)(Bg32 + k0);
            const float4 b1 = *(const float4*)(Bg32 + k0 + 4);
            const float4 b2 = *(const float4*)(Bg32 + k0 + 8);
            const float4 b3 = *(const float4*)(Bg32 + k0 + 12);
            bv[0]=b0.x; bv[1]=b0.y; bv[2]=b0.z; bv[3]=b0.w;
            bv[4]=b1.x; bv[5]=b1.y; bv[6]=b1.z; bv[7]=b1.w;
            bv[8]=b2.x; bv[9]=b2.y; bv[10]=b2.z; bv[11]=b2.w;
            bv[12]=b3.x; bv[13]=b3.y; bv[14]=b3.z; bv[15]=b3.w;
        }

        __syncthreads();  // all waves done reading previous tile

        if constexpr (AM == 0) {
            if constexpr (BM == 0) {
#pragma unroll
                for (int q = 0; q < 8; ++q)
                    gll16(gPre + (size_t)q * 16 * K + k0, &lds[ldsPre + q * 512]);
            } else {
                if (wid < 2) {
#pragma unroll
                    for (int q = 0; q < 8; ++q)
                        gll16(gPre + (size_t)q * 16 * K + k0, &lds[ldsPre + q * 512]);
                }
            }
        } else {
#pragma unroll
            for (int q = 0; q < 4; ++q)
                gll16(gB + (size_t)q * 16 * K + k0, &lds[ldsB + (sib0 + q) * 512]);
        }

        if constexpr (AM != 0) {
            uint4 h0, h1, l0, l1;
            cvt16(av, h0, h1, l0, l1);
            *(uint4*)&lds[sw0] = h0;
            *(uint4*)&lds[sw1] = h1;
            *(uint4*)&lds[4096 + sw0] = l0;
            *(uint4*)&lds[4096 + sw1] = l1;
        }
        if constexpr (BM != 0) {
            uint4 h0, h1, l0, l1;
            cvt16(bv, h0, h1, l0, l1);
            *(uint4*)&lds[8192 + sw0] = h0;
            *(uint4*)&lds[8192 + sw1] = h1;
            *(uint4*)&lds[12288 + sw0] = l0;
            *(uint4*)&lds[12288 + sw1] = l1;
        }
        __syncthreads();  // drains vmcnt(0): gll data + converted writes visible

        bf16x8 fah[4], fal[4];
#pragma unroll
        for (int i = 0; i < 4; ++i) {
            const int ao = (wr * 64 + i * 16 + fr) * 32 + fsw;
            fah[i] = *(const bf16x8*)&lds[ao];
            fal[i] = *(const bf16x8*)&lds[4096 + ao];
        }
#pragma unroll
        for (int j = 0; j < 4; ++j) {
            const int bo = (wc * 64 + j * 16 + fr) * 32 + fsw;
            const bf16x8 fbh = *(const bf16x8*)&lds[8192 + bo];
            const bf16x8 fbl = *(const bf16x8*)&lds[12288 + bo];
#pragma unroll
            for (int i = 0; i < 4; ++i) {
                acc[i][j] = __builtin_amdgcn_mfma_f32_16x16x32_bf16(fah[i], fbh, acc[i][j], 0, 0, 0);
                acc[i][j] = __builtin_amdgcn_mfma_f32_16x16x32_bf16(fal[i], fbh, acc[i][j], 0, 0, 0);
                acc[i][j] = __builtin_amdgcn_mfma_f32_16x16x32_bf16(fah[i], fbl, acc[i][j], 0, 0, 0);
            }
        }
    }

    // C/D layout: col = lane&15 (fr), row = fh*4 + reg (verified round 1)
    const size_t cz = (size_t)z * (size_t)bsC;
#pragma unroll
    for (int i = 0; i < 4; ++i) {
        const int rbase = row0 + wr * 64 + i * 16 + fh * 4;
#pragma unroll
        for (int j = 0; j < 4; ++j) {
            const int c = col0 + wc * 64 + j * 16 + fr;
            float bcol = 0.f, sc = 0.f, sh = 0.f;
            if constexpr (EPI != 3) bcol = bias[c];
            if constexpr (EPI == 1) {
                const int b = rbase >> 8;
                sc = scl[b * DD + c];
                sh = shf[b * DD + c];
            }
#pragma unroll
            for (int r = 0; r < 4; ++r) {
                const int rr = rbase + r;
                const size_t idx = cz + (size_t)rr * N + c;
                const float t = acc[i][j][r] + ((EPI == 3) ? bias[rr] : bcol);
                if constexpr (EPI == 0) C[idx] = t;
                else if constexpr (EPI == 1) C[idx] = fmaf(t0[idx], sc, sh) + t;
                else C[idx] = resid[idx] + silu_f(t);
            }
        }
    }
}

// ---------------------------------------------------------------------------
// AdaIN stats: per (b,d) channel over s.
// ---------------------------------------------------------------------------
__global__ __launch_bounds__(256)
void adain_stats(const float* __restrict__ t0, const float* __restrict__ style,
                 float* __restrict__ scl, float* __restrict__ shf)
{
    const int idx = blockIdx.x * 256 + threadIdx.x;
    const int b = idx >> 10;
    const int d = idx & (DD - 1);
    const float* pc = t0    + (size_t)b * SS * DD + d;
    const float* ps = style + (size_t)b * SS * DD + d;
    float sc = 0.f, sc2 = 0.f, ss = 0.f, ss2 = 0.f;
    for (int s = 0; s < SS; ++s) {
        const float c  = pc[(size_t)s * DD];
        const float st = ps[(size_t)s * DD];
        sc += c;  sc2 = fmaf(c, c, sc2);
        ss += st; ss2 = fmaf(st, st, ss2);
    }
    const float mc = sc * (1.0f / SS);
    const float ms = ss * (1.0f / SS);
    float vc = (sc2 - (float)SS * mc * mc) * (1.0f / (SS - 1));
    float vs = (ss2 - (float)SS * ms * ms) * (1.0f / (SS - 1));
    vc = fmaxf(vc, 0.f);
    vs = fmaxf(vs, 0.f);
    const float csd = sqrtf(vc + 1e-5f);
    const float ssd = sqrtf(vs + 1e-5f);
    const float sca = ssd / csd;
    scl[idx] = sca;
    shf[idx] = ms - mc * sca;
}

// ---------------------------------------------------------------------------
// LN stats only: per-row mu, rsqrt(var+eps) over D.
// ---------------------------------------------------------------------------
__global__ __launch_bounds__(256)
void ln_stats(const float* __restrict__ X, float* __restrict__ mu, float* __restrict__ rs)
{
    const int row = blockIdx.x * 4 + (threadIdx.x >> 6);
    const int lane = threadIdx.x & 63;
    const float* xr = X + (size_t)row * DD;
    float sum = 0.f, sq = 0.f;
#pragma unroll
    for (int c = 0; c < 4; ++c) {
        const float4 v = *(const float4*)&xr[c * 256 + lane * 4];
        sum += v.x + v.y + v.z + v.w;
        sq += v.x * v.x + v.y * v.y + v.z * v.z + v.w * v.w;
    }
#pragma unroll
    for (int off = 32; off > 0; off >>= 1) {
        sum += __shfl_down(sum, off, 64);
        sq  += __shfl_down(sq,  off, 64);
    }
    if (lane == 0) {
        const float m = sum * (1.0f / DD);
        float var = sq * (1.0f / DD) - m * m;
        var = fmaxf(var, 0.f);
        mu[row] = m;
        rs[row] = rsqrtf(var + 1e-5f);
    }
}

// ---------------------------------------------------------------------------
// LN0 apply + transpose + bf16 split: y = LN(x1) -> yT[b][d][s] hi/lo,
// chunk-swizzled per d-row so the GEMM B-path reads conflict-free.
// Block: 64s x 64d tile of one batch; LDS transpose (stride 66 u16).
// ---------------------------------------------------------------------------
__global__ __launch_bounds__(256)
void ln_t_split(const float* __restrict__ X, const float* __restrict__ mu,
                const float* __restrict__ rs, const float* __restrict__ g,
                const float* __restrict__ beta,
                u16* __restrict__ yTh, u16* __restrict__ yTl)
{
    __shared__ u16 th[64 * 66];
    __shared__ u16 tl[64 * 66];
    const int b = blockIdx.z;
    const int s0 = blockIdx.y * 64;
    const int d0 = blockIdx.x * 64;
    const int t = threadIdx.x;
    const int sl0 = t >> 4;
    const int dl4 = (t & 15) * 4;
    const float4 gv = *(const float4*)&g[d0 + dl4];
    const float4 bv = *(const float4*)&beta[d0 + dl4];
#pragma unroll
    for (int q = 0; q < 4; ++q) {
        const int s_local = q * 16 + sl0;
        const int row = b * SS + s0 + s_local;
        const float4 v = *(const float4*)&X[(size_t)row * DD + d0 + dl4];
        const float m = mu[row], r = rs[row];
        const float vals[4] = {(v.x - m) * r * gv.x + bv.x, (v.y - m) * r * gv.y + bv.y,
                               (v.z - m) * r * gv.z + bv.z, (v.w - m) * r * gv.w + bv.w};
#pragma unroll
        for (int j = 0; j < 4; ++j) {
            u16 hh, lo;
            splitf(vals[j], hh, lo);
            th[(dl4 + j) * 66 + s_local] = hh;
            tl[(dl4 + j) * 66 + s_local] = lo;
        }
    }
    __syncthreads();
    const int dl = t >> 2;            // 0..63: local d row
    const int sc = (t & 3) * 16;      // 0,16,32,48: local s start
    u32 ah[8], al[8];
#pragma unroll
    for (int jj = 0; jj < 8; ++jj) {
        ah[jj] = *(const u32*)&th[dl * 66 + sc + jj * 2];
        al[jj] = *(const u32*)&tl[dl * 66 + sc + jj * 2];
    }
    const int cc0 = (s0 + sc) >> 3;   // even logical chunk index
    const int swv = swz4(dl & 15);    // d-row swizzle (d0 multiple of 64)
    const int p0 = (cc0 & ~3) | ((cc0 & 3) ^ swv);
    const int p1 = (cc0 & ~3) | ((((cc0 & 3) + 1)) ^ swv);
    const size_t rb = ((size_t)b * DD + d0 + dl) * SS;
    *(uint4*)&yTh[rb + p0 * 8] = make_uint4(ah[0], ah[1], ah[2], ah[3]);
    *(uint4*)&yTh[rb + p1 * 8] = make_uint4(ah[4], ah[5], ah[6], ah[7]);
    *(uint4*)&yTl[rb + p0 * 8] = make_uint4(al[0], al[1], al[2], al[3]);
    *(uint4*)&yTl[rb + p1 * 8] = make_uint4(al[4], al[5], al[6], al[7]);
}

// ---------------------------------------------------------------------------
// LN1 full (stats + affine) + bf16 split row-major, chunk-swizzled: z -> zh/zl.
// One wave per row; lane owns 16 consecutive d (= 2 chunks).
// ---------------------------------------------------------------------------
__global__ __launch_bounds__(256)
void ln_split(const float* __restrict__ X, const float* __restrict__ g,
              const float* __restrict__ beta, u16* __restrict__ zh, u16* __restrict__ zl)
{
    const int row = blockIdx.x * 4 + (threadIdx.x >> 6);
    const int lane = threadIdx.x & 63;
    const float* xr = X + (size_t)row * DD;
    float4 v[4];
    float sum = 0.f, sq = 0.f;
#pragma unroll
    for (int q = 0; q < 4; ++q) {
        v[q] = *(const float4*)&xr[lane * 16 + q * 4];
        sum += v[q].x + v[q].y + v[q].z + v[q].w;
        sq += v[q].x * v[q].x + v[q].y * v[q].y + v[q].z * v[q].z + v[q].w * v[q].w;
    }
#pragma unroll
    for (int off = 32; off > 0; off >>= 1) {
        sum += __shfl_down(sum, off, 64);
        sq  += __shfl_down(sq,  off, 64);
    }
    sum = __shfl(sum, 0, 64);
    sq  = __shfl(sq,  0, 64);
    const float m = sum * (1.0f / DD);
    float var = sq * (1.0f / DD) - m * m;
    var = fmaxf(var, 0.f);
    const float r = rsqrtf(var + 1e-5f);
    float ov[16];
#pragma unroll
    for (int q = 0; q < 4; ++q) {
        const float4 gq = *(const float4*)&g[lane * 16 + q * 4];
        const float4 bq = *(const float4*)&beta[lane * 16 + q * 4];
        ov[q * 4 + 0] = (v[q].x - m) * r * gq.x + bq.x;
        ov[q * 4 + 1] = (v[q].y - m) * r * gq.y + bq.y;
        ov[q * 4 + 2] = (v[q].z - m) * r * gq.z + bq.z;
        ov[q * 4 + 3] = (v[q].w - m) * r * gq.w + bq.w;
    }
    uint4 h0, h1, l0, l1;
    cvt16(ov, h0, h1, l0, l1);
    const int swr = swz4(row & 15);
    const int c0 = lane * 2;
    const int p0 = (c0 & ~3) | ((c0 & 3) ^ swr);
    const int p1 = ((c0 + 1) & ~3) | (((c0 + 1) & 3) ^ swr);
    u16* zr = zh + (size_t)row * DD;
    u16* zr2 = zl + (size_t)row * DD;
    *(uint4*)&zr[p0 * 8]  = h0;
    *(uint4*)&zr[p1 * 8]  = h1;
    *(uint4*)&zr2[p0 * 8] = l0;
    *(uint4*)&zr2[p1 * 8] = l1;
}

// ---------------------------------------------------------------------------
// Copy embed/style passthrough outputs.
// ---------------------------------------------------------------------------
__global__ __launch_bounds__(256)
void copy_pass(const float4* __restrict__ emb, const float4* __restrict__ sty,
               float4* __restrict__ out_emb, float4* __restrict__ out_sty)
{
    const int n4 = MM * DD / 4;
    const int stride = gridDim.x * blockDim.x;
    for (int i = blockIdx.x * blockDim.x + threadIdx.x; i < n4; i += stride) {
        out_emb[i] = emb[i];
        out_sty[i] = sty[i];
    }
}

extern "C" void kernel_launch(void* const* d_in, const int* in_sizes, int n_in,
                              void* d_out, int out_size, void* d_ws, size_t ws_size,
                              hipStream_t stream)
{
    const float* x     = (const float*)d_in[0];
    const float* embed = (const float*)d_in[1];
    const float* style = (const float*)d_in[2];
    const float* Wc    = (const float*)d_in[3];
    const float* bc    = (const float*)d_in[4];
    const float* We    = (const float*)d_in[5];
    const float* be    = (const float*)d_in[6];
    const float* W0    = (const float*)d_in[7];
    const float* b0    = (const float*)d_in[8];
    const float* W1    = (const float*)d_in[9];
    const float* b1    = (const float*)d_in[10];
    const float* g0    = (const float*)d_in[11];
    const float* beta0 = (const float*)d_in[12];
    const float* g1    = (const float*)d_in[13];
    const float* beta1 = (const float*)d_in[14];

    float* out     = (float*)d_out;
    float* out_x   = out;                        // R0: scratch until s7 writes final x
    float* out_emb = out + (size_t)MM * DD;      // R1: buf1 (x1/x2), embed at end
    float* out_sty = out + (size_t)2 * MM * DD;  // R2: buf0 (t0 -> yT -> z), style at end

    float* buf0 = out_sty;
    float* buf1 = out_emb;

    // All scratch lives in R0 (dead tenants by the time s7 overwrites it).
    // d_ws is intentionally UNUSED (ws_size unknown; round-2 crash suspect).
    u16* Wch = (u16*)out_x;                // [1024][2048] hi   (4 MB)  dead after s1
    u16* Wcl = Wch + 2097152;              //              lo   (4 MB)
    u16* Weh = Wcl + 2097152;              // [1024][1024] hi   (2 MB)  dead after s3
    u16* Wel = Weh + 1048576;              //              lo   (2 MB)
    u16* W0h = Wel + 1048576;              // [256][256]   hi (128 KB)  dead after s5
    u16* W0l = W0h + 65536;                //              lo
    float* scl = (float*)(W0l + 65536);    // [B*D] (256 KB)            dead after s3
    float* shf = scl + BB * DD;            // [B*D]
    float* muv = shf + BB * DD;            // [M]   (64 KB)             dead after s4
    float* rsv = muv + MM;                 // [M]
    // total ~13.5 MB < 64 MB (R0)

    // bf16 activation buffers carved from R2 epochs
    u16* yTh = (u16*)buf0;                 // [B][D][S] after t0 dead (32 MB)
    u16* yTl = yTh + (size_t)MM * DD;      //                         (32 MB)
    u16* zh  = (u16*)buf0;                 // [M][D] after yT dead
    u16* zl  = zh + (size_t)MM * DD;

    const dim3 gNT(DD / 128, MM / 128, 1);  // (8,128)

    // 0) weight pre-split (chunk-swizzled); W1 is converted in-kernel in s7
    split_w<<<1024, 256, 0, stream>>>(Wc, Wch, Wcl, 8);  // K=2048
    split_w<<<512, 256, 0, stream>>>(We, Weh, Wel, 7);   // K=1024
    split_w<<<32, 256, 0, stream>>>(W0, W0h, W0l, 5);    // K=256

    // 1) t0 = x @ Wc^T + bc           (A fp32 convert, B pre-split)
    gemm_bf3<1, 0, 0><<<gNT, 256, 0, stream>>>(
        x, nullptr, nullptr, nullptr, Wch, Wcl, bc, nullptr, nullptr, nullptr,
        nullptr, buf0, MM, DD, 2 * DD, 0, 0);
    // 2) AdaIN stats
    adain_stats<<<BB * DD / 256, 256, 0, stream>>>(buf0, style, scl, shf);
    // 3) x1 = adain(t0) + silu(embed) @ We^T + be
    gemm_bf3<2, 0, 1><<<gNT, 256, 0, stream>>>(
        embed, nullptr, nullptr, nullptr, Weh, Wel, be, buf0, scl, shf,
        nullptr, buf1, MM, DD, DD, 0, 0);
    // 4) LN0 stats, then apply+transpose+split: yT[b][d][s] (swizzled)
    ln_stats<<<MM / 4, 256, 0, stream>>>(buf1, muv, rsv);
    ln_t_split<<<dim3(16, 4, 64), 256, 0, stream>>>(buf1, muv, rsv, g0, beta0, yTh, yTl);
    // 5) x2 = x1 + silu(W0 @ y + b0): batched NT MFMA, in-place on buf1
    gemm_bf3<0, 0, 3><<<dim3(8, 2, 64), 256, 0, stream>>>(
        nullptr, W0h, W0l, nullptr, yTh, yTl, b0, nullptr, nullptr, nullptr,
        buf1, buf1, SS, DD, SS, 262144LL, 262144LL);
    // 6) z = LN(x2) -> bf16 hi/lo (swizzled)
    ln_split<<<MM / 4, 256, 0, stream>>>(buf1, g1, beta1, zh, zl);
    // 7) out_x = x2 + silu(z @ W1^T + b1)   (A pre-split via gll, B=W1 fp32 convert)
    gemm_bf3<0, 1, 2><<<gNT, 256, 0, stream>>>(
        nullptr, zh, zl, W1, nullptr, nullptr, b1, nullptr, nullptr, nullptr,
        buf1, out_x, MM, DD, DD, 0, 0);
    // 8) passthrough outputs
    copy_pass<<<4096, 256, 0, stream>>>((const float4*)embed, (const float4*)style,
                                        (float4*)out_emb, (float4*)out_sty);
}